// Round 1
// baseline (316.539 us; speedup 1.0000x reference)
//
#include <hip/hip_runtime.h>

// SparseMaxPool — R8. Theory: kernel portion (~104us of dur; the other ~164us
// is the harness re-poison fill) runs at 2.6 TB/s vs the fill's 6.5 TB/s on
// the same buffer => store-stream-concurrency-limited, not write-path-limited.
// R7's 16 KB full-tile LDS capped residency at 8 single-wave blocks/CU with
// bursty 16-store windows between ~2000-cycle shuffle chains.
//
// R8: compact LDS (64 diag + 1040 stage outputs + 1 zero slot = 1105 floats,
// 4.4 KB/tile). Scatter is stride-1 (conflict-free). Emit gathers each output
// float4 from compact LDS via per-lane STATIC u16 byte offsets precomputed
// once per block (32 packed VGPRs); zero positions read the shared zero slot
// (same-address broadcast = free). __launch_bounds__(64,8) forces <=64 VGPR
// => 32 waves/CU (4x R7). Grid 8224 blocks x 2 tiles: all resident, one round.

constexpr int S_LEN[31] = {
  63,62,61,60,59,58,57,56,55,54,53,52,51,50,49,
  24,23,22,21,20,19,18,17,
  8,7,6,5,4,3,2,1};

// Compact base of stage m's output vector (after 64 diag slots).
constexpr int sbase(int m) {
  int b = 64;
  for (int i = 0; i < m; ++i) b += S_LEN[i];
  return b;
}
static_assert(sbase(30) + S_LEN[30] == 1104, "compact size");

// Closed-form bases used by the emit-index builder must match sbase():
// st=1 stages m=0..14 (off=m+1), st=2 m=15..22 (off=17+2mm), st=4 m=23..30
// (off=35+4mm). Validity given c<=63 reduces to: off in pattern AND st | r.
constexpr bool bases_ok() {
  for (int off = 1; off <= 15; ++off)
    if (64 + 63 * (off - 1) - (off - 1) * (off - 2) / 2 != sbase(off - 1)) return false;
  for (int mm = 0; mm < 8; ++mm)
    if (904 + 24 * mm - mm * (mm - 1) / 2 != sbase(15 + mm)) return false;
  for (int mm = 0; mm < 8; ++mm)
    if (1068 + 8 * mm - mm * (mm - 1) / 2 != sbase(23 + mm)) return false;
  return true;
}
static_assert(bases_ok(), "closed-form emit bases disagree with scatter bases");

// Compact float-index for output element (r,c); 1104 = zero slot.
__device__ __forceinline__ int cidx_of(int r, int c) {
  const int off = c - r;
  int idx = 1104;
  if (off == 0) idx = r;                                   // diagonal: x[r]
  if (off >= 1 && off <= 15) {                             // st=1 stages
    const int m = off - 1;
    idx = 64 + 63 * m - m * (m - 1) / 2 + r;
  }
  if (off >= 17 && off <= 31 && (off & 1) && !(r & 1)) {   // st=2 stages
    const int mm = (off - 17) >> 1;
    idx = 904 + 24 * mm - mm * (mm - 1) / 2 + (r >> 1);
  }
  if (off >= 35 && off <= 63 && !((off - 35) & 3) && !(r & 3)) { // st=4
    const int mm = (off - 35) >> 2;
    idx = 1068 + 8 * mm - mm * (mm - 1) / 2 + (r >> 2);
  }
  return idx;
}

__global__ void __launch_bounds__(64, 8)
sparse_pool_kernel(const float* __restrict__ x, float* __restrict__ out,
                   int nrows, int ntiles) {
  __shared__ float comp[1105];          // 4.4 KB: compact tile + zero slot
  const int lane = threadIdx.x;

  if (lane == 0) comp[1104] = 0.0f;     // shared zero slot, never rewritten

  // Issue first input load early; precompute hides its latency.
  int t = blockIdx.x;
  float curx = 0.f;
  if (t < ntiles) curx = (t < nrows) ? x[(size_t)t * 64 + lane] : 1.0f;

  // Per-lane emit gather offsets (byte offsets into comp), 2x u16 per u32.
  // Tile-invariant: computed once per block (one ~2us bubble at kernel start,
  // all 8224 blocks co-resident).
  uint32_t idxp[32];
#pragma unroll
  for (int it = 0; it < 16; ++it) {
    const int r  = it * 4 + (lane >> 4);     // float4 q=it*64+lane -> row q/16
    const int c0 = (lane & 15) * 4;          // -> col (q%16)*4
    idxp[2 * it] =
        (uint32_t)(cidx_of(r, c0 + 0) * 4) |
        ((uint32_t)(cidx_of(r, c0 + 1) * 4) << 16);
    idxp[2 * it + 1] =
        (uint32_t)(cidx_of(r, c0 + 2) * 4) |
        ((uint32_t)(cidx_of(r, c0 + 3) * 4) << 16);
  }

  for (; t < ntiles; t += gridDim.x) {
    // Diagonal + 31-stage pool chain (verified shuffles, unchanged from R7),
    // scattering compactly: stage m -> comp[sbase(m) + lane], stride-1.
    comp[lane] = curx;
    float cur = curx;
#pragma unroll
    for (int m = 0; m < 31; ++m) {
      if (m == 15 || m == 23) {              // k=3, s=2
        float a = __shfl(cur, 2 * lane);
        float b = __shfl(cur, 2 * lane + 1);
        float c = __shfl(cur, 2 * lane + 2);
        cur = fmaxf(fmaxf(a, b), c);
      } else {                               // k=2, s=1
        cur = fmaxf(cur, __shfl_down(cur, 1));
      }
      if (lane < S_LEN[m]) comp[sbase(m) + lane] = cur;
    }

    // Prefetch next tile's input; overlaps the emit below.
    const int tn = t + gridDim.x;
    float nx = 0.f;
    if (tn < ntiles) nx = (tn < nrows) ? x[(size_t)tn * 64 + lane] : 1.0f;

    // Emit: 16x { 4x ds_read_b32 gather + global_store_dwordx4 }, coalesced.
    // Wave-in-order DS guarantees these reads complete before next tile's
    // scatter overwrites comp.
    float4* o4 = (float4*)(out + (size_t)t * 4096);
    const char* cb = (const char*)comp;
#pragma unroll
    for (int it = 0; it < 16; ++it) {
      const uint32_t wa = idxp[2 * it], wb = idxp[2 * it + 1];
      float4 v;
      v.x = *(const float*)(cb + (wa & 0xffffu));
      v.y = *(const float*)(cb + (wa >> 16));
      v.z = *(const float*)(cb + (wb & 0xffffu));
      v.w = *(const float*)(cb + (wb >> 16));
      o4[it * 64 + lane] = v;
    }

    curx = nx;
  }
}

extern "C" void kernel_launch(void* const* d_in, const int* in_sizes, int n_in,
                              void* d_out, int out_size, void* d_ws, size_t ws_size,
                              hipStream_t stream) {
  const float* x = (const float*)d_in[0];        // fp32 input (32,512,64)
  float* out = (float*)d_out;                    // fp32 output

  const int nx     = in_sizes[0];                // B*D*64 = 1048576
  const int nrows  = nx / 64;                    // 16384 map tiles
  const int ntiles = out_size / 4096;            // 16448 = map + mask tiles

  // 2 tiles per block: 8224 blocks of 1 wave, 4.4 KB LDS, <=64 VGPR
  // -> 32 resident waves/CU (vs 8 in R7), single scheduling round.
  const int blocks = (ntiles + 1) / 2;
  sparse_pool_kernel<<<dim3(blocks), 64, 0, stream>>>(x, out, nrows, ntiles);
}

// Round 2
// 259.416 us; speedup vs baseline: 1.2202x; 1.2202x over previous
//
#include <hip/hip_runtime.h>

// SparseMaxPool — R9. R8 post-mortem: regression was self-inflicted (per-block
// gather-index precompute amortized over only 2 tiles, 64 scattered ds_read_b32
// per emit, and idxp[32] under a forced 64-VGPR cap => likely scratch spills).
// It did NOT cleanly test store concurrency. R9 returns to R7's proven
// structure (full 16 KB tile zeroed once, conflict-free scatter, 16x
// ds_read_b128 + global_store_dwordx4 emit) with exactly two changes:
//
//  1. NO global loads in the steady loop: grid = 4112 blocks x exactly 4
//     tiles (4112*4 = 16448), all 4 inputs loaded in the prologue into
//     statically-indexed registers. Loads and stores share vmcnt on CDNA;
//     R7's mid-loop prefetch could force emit-store drains at its use point.
//     With zero loads after the prologue, stores are never waited on.
//  2. Occupancy 8 -> 10 blocks/CU (16 KB x 10 = 160 KB exact LDS fit);
//     R7's 2056-block grid delivered only 8 resident.

constexpr int S_LEN[31] = {
  63,62,61,60,59,58,57,56,55,54,53,52,51,50,49,
  24,23,22,21,20,19,18,17,
  8,7,6,5,4,3,2,1};
constexpr int S_ST[31] = {
  1,1,1,1,1,1,1,1,1,1,1,1,1,1,1,
  2,2,2,2,2,2,2,2,
  4,4,4,4,4,4,4,4};
constexpr int S_OFF[31] = {
  1,2,3,4,5,6,7,8,9,10,11,12,13,14,15,
  17,19,21,23,25,27,29,31,
  35,39,43,47,51,55,59,63};

// Chain + scatter + emit for one tile. Verified shuffle geometry (absmax 0.0
// across R4-R9 lineage) — unchanged from R7.
__device__ __forceinline__ void process_tile(float* __restrict__ tile, int lane,
                                             float curx,
                                             float* __restrict__ optr) {
  // Diagonal (st=1 pattern: bank = lane%32, 2-way across the wave = free).
  tile[lane * 65] = curx;

  float cur = curx;
#pragma unroll
  for (int m = 0; m < 31; ++m) {
    if (m == 15 || m == 23) {             // k=3, s=2
      float a = __shfl(cur, 2 * lane);
      float b = __shfl(cur, 2 * lane + 1);
      float c = __shfl(cur, 2 * lane + 2);
      cur = fmaxf(fmaxf(a, b), c);
    } else {                              // k=2, s=1
      cur = fmaxf(cur, __shfl_down(cur, 1));
    }
    if (lane < S_LEN[m]) tile[lane * (S_ST[m] * 65) + S_OFF[m]] = cur;
  }

  // Emit: 16x (ds_read_b128 + global_store_dwordx4), fully coalesced, fixed
  // LDS addresses. Per-wave DS ordering makes next tile's scatter safe.
  float4* o4 = (float4*)optr;
  const float4* t4 = (const float4*)tile;
#pragma unroll
  for (int it = 0; it < 16; ++it)
    o4[it * 64 + lane] = t4[it * 64 + lane];
}

__global__ void __launch_bounds__(64)
sparse_pool_kernel(const float* __restrict__ x, float* __restrict__ out,
                   int nrows, int ntiles) {
  __shared__ float tile[4096];            // 16 KB -> 10 blocks/CU
  const int lane = threadIdx.x;
  const int t0 = blockIdx.x;
  const int stride = gridDim.x;

  // Prologue: issue ALL input loads now (4 independent global loads).
  // Defaults: 1.0f for mask tiles (t >= nrows); value unused if t >= ntiles.
  float xv0 = 1.0f, xv1 = 1.0f, xv2 = 1.0f, xv3 = 1.0f;
  if (t0 < nrows)                xv0 = x[(size_t)t0 * 64 + lane];
  if (t0 + stride < nrows)       xv1 = x[((size_t)t0 + stride) * 64 + lane];
  if (t0 + 2 * stride < nrows)   xv2 = x[((size_t)t0 + 2 * stride) * 64 + lane];
  if (t0 + 3 * stride < nrows)   xv3 = x[((size_t)t0 + 3 * stride) * 64 + lane];

  // Zero the tile ONCE (overlaps the loads). Valid positions are overwritten
  // every tile; the zero background persists (valid set is tile-invariant).
  const float4 z = make_float4(0.f, 0.f, 0.f, 0.f);
#pragma unroll
  for (int i = 0; i < 16; ++i)
    ((float4*)tile)[i * 64 + lane] = z;

  // Steady state: zero global loads -> no vmcnt waits -> stores free-running.
  if (t0 < ntiles)
    process_tile(tile, lane, xv0, out + (size_t)t0 * 4096);
  if (t0 + stride < ntiles)
    process_tile(tile, lane, xv1, out + ((size_t)t0 + stride) * 4096);
  if (t0 + 2 * stride < ntiles)
    process_tile(tile, lane, xv2, out + ((size_t)t0 + 2 * stride) * 4096);
  if (t0 + 3 * stride < ntiles)
    process_tile(tile, lane, xv3, out + ((size_t)t0 + 3 * stride) * 4096);
}

extern "C" void kernel_launch(void* const* d_in, const int* in_sizes, int n_in,
                              void* d_out, int out_size, void* d_ws, size_t ws_size,
                              hipStream_t stream) {
  const float* x = (const float*)d_in[0];        // fp32 input (32,512,64)
  float* out = (float*)d_out;                    // fp32 output

  const int nx     = in_sizes[0];                // B*D*64 = 1048576
  const int nrows  = nx / 64;                    // 16384 map tiles
  const int ntiles = out_size / 4096;            // 16448 = map + mask tiles

  // Exactly 4 tiles per block (4112 * 4 = 16448): uniform block duration,
  // prologue-loaded inputs, 10 blocks/CU resident (160 KB LDS exact fit).
  const int blocks = (ntiles + 3) / 4;
  sparse_pool_kernel<<<dim3(blocks), 64, 0, stream>>>(x, out, nrows, ntiles);
}